// Round 17
// baseline (137.320 us; speedup 1.0000x reference)
//
#include <hip/hip_runtime.h>

// VectorQuantizer: x (64,32,32,128) f32, embeddings (128,1024) f32.
// out = x + (q - x), q = e.T[argmin_k ||x_row - e_k||^2]
//
// Cascade (each stage only needs enough precision to RANK):
//   phase 1 (hi-bf16 MFMA, swapped operands A=codes/B=x-rows): per-row argmin
//     in-lane over packed keys (m = dot - nrm/2, 8-bit local code id in mantissa
//     LSBs); -nrm/2 folded in via 9th MFMA whose A-operand comes from REGISTERS
//     (hl[8] pre-loaded from global; no per-t LDS read -> no lgkm stall in loop).
//     Grid = 256 rowgroups x 4 quarters (r15 geometry, best measured; Q=8's
//     extra xp re-reads regressed r16). 2 rowtiles/wave, top-2 via v_med3_f32,
//     pb [q][row]. (256,2): proven no-spill cap (r13: (256,3) -> spill disaster).
//   k_finish (merge+gather fused): merge 4 quarters/row -> code; STE-gather;
//     gap < MARGIN1 -> worklist (provisional output, corrected by rescan).
//   k_rescan: EXACT f64 re-argmin of flagged rows (4 rows/block, r11-proven
//     register budget), writes corrected output rows directly.
// 4 dispatches (wlc cleared by prep).
// C/D layout col=lane&31, reg->(r&3)+8*(r>>2)+4*(lane>>5); k-bijection symmetry
// and the 9th-MFMA nrm trick verified end-to-end rounds 3-16 (absmax 0).

#define NROWS 65536
#define DDIM 128
#define KCODES 1024
#define MARGIN1 0.30f    // s-space; hi-bf16 sigma ~0.05, cid noise ~0.016

typedef __attribute__((ext_vector_type(8))) short short8;
typedef __attribute__((ext_vector_type(16))) float f32x16;

__device__ inline ushort f2bf(float f) {            // RNE f32 -> bf16 bits
    union { float f; unsigned u; } v; v.f = f;
    unsigned r = v.u + 0x7fffu + ((v.u >> 16) & 1u);
    return (ushort)(r >> 16);
}
__device__ inline float bf2f(ushort b) {
    union { unsigned u; float f; } v; v.u = ((unsigned)b) << 16;
    return v.f;
}

__device__ inline void gload_lds16(const uint4* g, uint4* lds) {
    __builtin_amdgcn_global_load_lds((const __attribute__((address_space(1))) void*)g,
                                     (__attribute__((address_space(3))) void*)lds,
                                     16, 0, 0);
}

// ---------- fused prep: transpose + norms + e-hi pack + nrm hi/lo + x-hi pack ----------
// grid 4096 x 256.
__global__ void k_prep(const float* __restrict__ x, const float* __restrict__ e,
                       float* __restrict__ et, double* __restrict__ nrm64,
                       uint4* __restrict__ epq, unsigned* __restrict__ nhl,
                       uint4* __restrict__ xp, int* __restrict__ wlc) {
    const int gid = blockIdx.x * blockDim.x + threadIdx.x;

    if (gid == 0) { wlc[0] = 0; wlc[1] = 0; }

    // x-hi fragment pack (all threads): xp[rt*512 + c*64 + lane]
    {
        int lane = gid & 63, c = (gid >> 6) & 7, rt = gid >> 9;     // rt 0..2047
        int row = rt * 32 + (lane & 31);
        int kbase = c * 16 + ((lane >> 5) << 3);
        const float4* xr4 = reinterpret_cast<const float4*>(x + (size_t)row * DDIM + kbase);
        float4 u = xr4[0], v = xr4[1];
        float fv[8] = {u.x, u.y, u.z, u.w, v.x, v.y, v.z, v.w};
        union { ushort s[8]; uint4 q; } pk;
        #pragma unroll
        for (int j = 0; j < 8; ++j) pk.s[j] = f2bf(fv[j]);
        xp[gid] = pk.q;
    }

    // transpose (first 131072): et[k][d] = e[d][k]
    if (gid < 131072) {
        int d = gid >> 10, k = gid & 1023;
        et[k * DDIM + d] = e[gid];
    }

    // e-hi fragment pack (first 16384): epq[nt*512 + c*64 + lane]
    if (gid < 16384) {
        int lane = gid & 63, c = (gid >> 6) & 7, nt = gid >> 9;
        int col = nt * 32 + (lane & 31);
        int kbase = c * 16 + ((lane >> 5) << 3);
        union { ushort s[8]; uint4 q; } pk;
        #pragma unroll
        for (int j = 0; j < 8; ++j)
            pk.s[j] = f2bf(e[(kbase + j) * KCODES + col]);
        epq[(size_t)nt * 512 + c * 64 + lane] = pk.q;
    }

    // norms (threads 32768..40959): 8 lanes per code, shfl reduce
    if (gid >= 32768 && gid < 32768 + 8192) {
        int t2 = gid - 32768;
        int k = t2 >> 3, part = t2 & 7;
        double s = 0.0;
        #pragma unroll
        for (int j = 0; j < 16; ++j) {
            double v = (double)e[(part * 16 + j) * KCODES + k];
            s = fma(v, v, s);
        }
        #pragma unroll
        for (int m = 1; m < 8; m <<= 1) s += __shfl_xor(s, m);
        if (part == 0) {
            nrm64[k] = s;
            float t0 = (float)(-0.5 * s);
            ushort hb = f2bf(t0);
            ushort lb = f2bf(t0 - bf2f(hb));
            nhl[k] = (unsigned)hb | ((unsigned)lb << 16);
        }
    }
}

// ---------- phase 1: swapped-operand hi-bf16 MFMA argmin, quarter-split ----------
// grid 1024 = 256 rowgroups x 4 quarters. Block = 4 waves; each wave owns TWO
// rowtiles (interleaved MFMA chains). 64 KB LDS stage-once; barrier-free loop;
// nrm hi/lo bias words held in REGISTERS (hl[8]) -> no in-loop LDS reads.
__global__ __launch_bounds__(256, 2) void k_argmin32(const uint4* __restrict__ xp,
                                                     const uint4* __restrict__ epq,
                                                     const unsigned* __restrict__ nhl,
                                                     unsigned* __restrict__ pb1,
                                                     float* __restrict__ pb2) {
    __shared__ uint4 sbuf[4096];      // 64 KB: 8 e-hi tiles (256 codes)

    const int tid = threadIdx.x;
    const int lane = tid & 63;
    const int w = tid >> 6;
    const int kq = blockIdx.x & 3;                 // code quarter
    const int rg = blockIdx.x >> 2;                // rowgroup (256 rows)
    const int rtA = rg * 8 + w * 2;                // this wave's rowtiles
    const int rtB = rtA + 1;
    const int lrow = lane & 31;
    const int lgrp = lane >> 5;

    // stage quarter: 8 tiles (16 x 16B per thread)
    #pragma unroll
    for (int i = 0; i < 16; ++i)
        gload_lds16(epq + (size_t)kq * 4096 + i * 256 + tid,
                    &sbuf[i * 256 + (w << 6)]);

    // nrm bias words for this quarter's 8 tiles, straight to registers
    unsigned hl[8];
    #pragma unroll
    for (int t = 0; t < 8; ++t)
        hl[t] = nhl[kq * 256 + t * 32 + lrow];

    // x-hi fragments for both rowtiles (pre-packed, coalesced)
    short8 ahA[8], ahB[8];
    #pragma unroll
    for (int c = 0; c < 8; ++c) {
        union { uint4 q; short8 s; } ua, ub;
        ua.q = xp[(size_t)rtA * 512 + c * 64 + lane];
        ub.q = xp[(size_t)rtB * 512 + c * 64 + lane];
        ahA[c] = ua.s; ahB[c] = ub.s;
    }
    // 9th-MFMA B operand: ones at k=0,1
    short8 bx = {0, 0, 0, 0, 0, 0, 0, 0};
    if (lgrp == 0) { bx[0] = (short)0x3F80; bx[1] = (short)0x3F80; }
    const unsigned cid4 = (unsigned)(lgrp << 2);   // the only runtime cid bit

    asm volatile("s_waitcnt vmcnt(0)" ::: "memory");
    __syncthreads();                  // staged; barrier-free main loop

    float kA1 = -3.4e38f, kA2 = -3.4e38f;
    float kB1 = -3.4e38f, kB2 = -3.4e38f;

    for (int t = 0; t < 8; ++t) {
        f32x16 aA, aB;
        #pragma unroll
        for (int r = 0; r < 16; ++r) { aA[r] = 0.f; aB[r] = 0.f; }

        #pragma unroll
        for (int c = 0; c < 8; ++c) {
            union { uint4 q; short8 s; } ef;
            ef.q = sbuf[t * 512 + c * 64 + lane];
            aA = __builtin_amdgcn_mfma_f32_32x32x16_bf16(ef.s, ahA[c], aA, 0, 0, 0);
            aB = __builtin_amdgcn_mfma_f32_32x32x16_bf16(ef.s, ahB[c], aB, 0, 0, 0);
        }
        short8 ax = {0, 0, 0, 0, 0, 0, 0, 0};
        if (lgrp == 0) {
            ax[0] = (short)(hl[t] & 0xFFFF);
            ax[1] = (short)(hl[t] >> 16);
        }
        aA = __builtin_amdgcn_mfma_f32_32x32x16_bf16(ax, bx, aA, 0, 0, 0);
        aB = __builtin_amdgcn_mfma_f32_32x32x16_bf16(ax, bx, aB, 0, 0, 0);

        // 3 VALU per key: v_and_or pack, v_med3 (new 2nd-best), v_max (new best)
        #pragma unroll
        for (int r = 0; r < 16; ++r) {
            unsigned cid = (unsigned)((t << 5) | ((r & 3) + ((r >> 2) << 3))) | cid4;
            float keyA = __uint_as_float((__float_as_uint(aA[r]) & 0xFFFFFF00u) | cid);
            float keyB = __uint_as_float((__float_as_uint(aB[r]) & 0xFFFFFF00u) | cid);
            kA2 = __builtin_amdgcn_fmed3f(kA1, kA2, keyA);
            kA1 = fmaxf(kA1, keyA);
            kB2 = __builtin_amdgcn_fmed3f(kB1, kB2, keyB);
            kB1 = fmaxf(kB1, keyB);
        }
    }

    // combine the two 32-lane halves (sorted-pair merge via med3)
    {
        float o1 = __shfl_xor(kA1, 32);
        float o2 = __shfl_xor(kA2, 32);
        float m2 = __builtin_amdgcn_fmed3f(kA1, o1, fmaxf(kA2, o2));
        float m1 = fmaxf(kA1, o1);
        if (lane < 32) {                           // coalesced 128B wave-half write
            size_t o = (size_t)kq * NROWS + rtA * 32 + lrow;
            pb1[o] = __float_as_uint(m1);
            pb2[o] = m2;
        }
    }
    {
        float o1 = __shfl_xor(kB1, 32);
        float o2 = __shfl_xor(kB2, 32);
        float m2 = __builtin_amdgcn_fmed3f(kB1, o1, fmaxf(kB2, o2));
        float m1 = fmaxf(kB1, o1);
        if (lane < 32) {
            size_t o = (size_t)kq * NROWS + rtB * 32 + lrow;
            pb1[o] = __float_as_uint(m1);
            pb2[o] = m2;
        }
    }
}

// ---------- k_finish: merge 4 quarters + STE-gather, fused ----------
// grid 256 x 256: block owns 256 rows. Phase A: per-thread merge -> code in LDS,
// flagged rows -> worklist. Phase B: block streams 256 rows x 32 float4 out.
__global__ __launch_bounds__(256) void k_finish(const float* __restrict__ x,
                                                const float* __restrict__ et,
                                                const unsigned* __restrict__ pb1,
                                                const float* __restrict__ pb2,
                                                int* __restrict__ wlc,
                                                int* __restrict__ wl,
                                                float* __restrict__ out) {
    __shared__ int scode[256];
    const int tid = threadIdx.x;
    const int base = blockIdx.x * 256;
    const int r = base + tid;

    // merge ([q][row] layout: coalesced per-q loads)
    float best = -3.4e38f, sec = -3.4e38f;
    unsigned ub = 0; int bq = 0;
    #pragma unroll
    for (int q = 0; q < 4; ++q) {
        unsigned k1 = pb1[(size_t)q * NROWS + r];
        float    s2 = __uint_as_float(__float_as_uint(pb2[(size_t)q * NROWS + r]) & 0xFFFFFF00u);
        float    m  = __uint_as_float(k1 & 0xFFFFFF00u);
        bool t = m > best;
        sec = fmaxf(sec, fmaxf(s2, t ? best : m));
        ub = t ? k1 : ub;
        bq = t ? q : bq;
        best = t ? m : best;
    }
    scode[tid] = bq * 256 + (int)(ub & 255u);
    if (2.f * (best - sec) < MARGIN1) {                // s-gap = 2*(m1-m2)
        int slot = atomicAdd(wlc, 1);
        wl[slot] = r;
    }
    __syncthreads();

    // STE-gather: 256 rows x 32 float4 = 8192 float4, 32 per thread
    const float4* x4  = reinterpret_cast<const float4*>(x);
    const float4* et4 = reinterpret_cast<const float4*>(et);
    float4* o4 = reinterpret_cast<float4*>(out);
    #pragma unroll
    for (int i = 0; i < 32; ++i) {
        int j = i * 256 + tid;                         // 0..8191
        int rl = j >> 5, d4 = j & 31;
        size_t g = (size_t)(base + rl) * 32 + d4;
        float4 q = et4[(size_t)scode[rl] * 32 + d4];
        float4 xv = x4[g];
        float4 o;
        o.x = xv.x + (q.x - xv.x);
        o.y = xv.y + (q.y - xv.y);
        o.z = xv.z + (q.z - xv.z);
        o.w = xv.w + (q.w - xv.w);
        o4[g] = o;
    }
}

// ---------- rescan: EXACT f64 re-argmin + direct output write ----------
// 4 rows/block (r11-proven register budget: acc[4][4] f64).
__global__ __launch_bounds__(256) void k_rescan(const float* __restrict__ x,
                                                const float* __restrict__ e,
                                                const float* __restrict__ et,
                                                const double* __restrict__ nrm64,
                                                const int* __restrict__ wlc,
                                                const int* __restrict__ wl,
                                                float* __restrict__ out) {
    __shared__ float  xs[4][DDIM];
    __shared__ double rb1[4][256];
    __shared__ int    ri[4][256];
    const int tid = threadIdx.x, lane = tid & 63, wv = tid >> 6;
    const int n = *wlc;

    for (int i0 = blockIdx.x * 4; i0 < n; i0 += gridDim.x * 4) {
        if (tid < 128) {                   // 4 rows x 32 float4
            int j = tid >> 5, d4 = tid & 31;
            int ii = i0 + j;
            int row = wl[ii < n ? ii : i0];
            *reinterpret_cast<float4*>(&xs[j][d4 * 4]) =
                *reinterpret_cast<const float4*>(&x[(size_t)row * DDIM + d4 * 4]);
        }
        __syncthreads();

        double acc[4][4];
        #pragma unroll
        for (int kk = 0; kk < 4; ++kk)
            #pragma unroll
            for (int j = 0; j < 4; ++j) acc[kk][j] = 0.0;

        for (int d = 0; d < DDIM; d += 2) {
            double xv0[4], xv1[4];
            #pragma unroll
            for (int j = 0; j < 4; ++j) {
                xv0[j] = (double)xs[j][d];
                xv1[j] = (double)xs[j][d + 1];
            }
            #pragma unroll
            for (int kk = 0; kk < 4; ++kk) {
                double ev0 = (double)e[d * KCODES + kk * 256 + tid];       // coalesced
                double ev1 = (double)e[(d + 1) * KCODES + kk * 256 + tid];
                #pragma unroll
                for (int j = 0; j < 4; ++j) {
                    acc[kk][j] = fma(ev0, xv0[j], acc[kk][j]);
                    acc[kk][j] = fma(ev1, xv1[j], acc[kk][j]);
                }
            }
        }

        #pragma unroll
        for (int j = 0; j < 4; ++j) {
            double b1 = 1e300; int bi = 0;
            #pragma unroll
            for (int kk = 0; kk < 4; ++kk) {
                int k = kk * 256 + tid;                 // ascending per thread
                double s = nrm64[k] - 2.0 * acc[kk][j];
                if (s < b1) { b1 = s; bi = k; }
            }
            rb1[j][tid] = b1; ri[j][tid] = bi;
        }
        __syncthreads();

        // wave wv reduces row wv (first-min tiebreak), then writes the output row
        {
            double b1 = 1e300; int bi = 0x7FFFFFFF;
            #pragma unroll
            for (int p = 0; p < 4; ++p) {
                int t2 = lane + p * 64;
                double o1 = rb1[wv][t2]; int oi = ri[wv][t2];
                bool take = (o1 < b1) || (o1 == b1 && oi < bi);
                b1 = take ? o1 : b1;
                bi = take ? oi : bi;
            }
            #pragma unroll
            for (int m = 1; m < 64; m <<= 1) {
                double o1 = __shfl_xor(b1, m);
                int    oi = __shfl_xor(bi, m);
                bool take = (o1 < b1) || (o1 == b1 && oi < bi);
                b1 = take ? o1 : b1;
                bi = take ? oi : bi;
            }
            if (i0 + wv < n && lane < 32) {            // all lanes hold bi now
                int row = wl[i0 + wv];
                float4 q = reinterpret_cast<const float4*>(et)[(size_t)bi * 32 + lane];
                float4 xv = *reinterpret_cast<const float4*>(&xs[wv][lane * 4]);
                float4 o;
                o.x = xv.x + (q.x - xv.x);
                o.y = xv.y + (q.y - xv.y);
                o.z = xv.z + (q.z - xv.z);
                o.w = xv.w + (q.w - xv.w);
                reinterpret_cast<float4*>(out)[(size_t)row * 32 + lane] = o;
            }
        }
        __syncthreads();
    }
}

extern "C" void kernel_launch(void* const* d_in, const int* in_sizes, int n_in,
                              void* d_out, int out_size, void* d_ws, size_t ws_size,
                              hipStream_t stream) {
    const float* x = (const float*)d_in[0];
    const float* e = (const float*)d_in[1];
    float* out = (float*)d_out;

    // ws layout (f32 slot units; all segments 16B-aligned). ~4.3 MB.
    double*   nrm64 = (double*)d_ws;                     // 2048 slots
    float*    et    = (float*)d_ws + 2048;               // 131072
    int*      wlc   = (int*)(et + 131072);               // 4
    int*      wl    = wlc + 4;                           // 65536
    uint4*    epq   = (uint4*)(wl + NROWS);              // 16384 uint4 (e hi)
    unsigned* nhl   = (unsigned*)(epq + 16384);          // 1024
    unsigned* pb1   = nhl + 1024;                        // 4*65536  [q][row]
    float*    pb2   = (float*)(pb1 + 4 * NROWS);         // 4*65536  [q][row]
    // x-hi fragment pack lives in d_out (16 MB < 32 MB); k_finish overwrites it.
    uint4*    xp    = (uint4*)d_out;

    k_prep<<<4096, 256, 0, stream>>>(x, e, et, nrm64, epq, nhl, xp, wlc);
    k_argmin32<<<1024, 256, 0, stream>>>(xp, epq, nhl, pb1, pb2);
    k_finish<<<NROWS / 256, 256, 0, stream>>>(x, et, pb1, pb2, wlc, wl, out);
    k_rescan<<<1024, 256, 0, stream>>>(x, e, et, nrm64, wlc, wl, out);
}

// Round 18
// 137.230 us; speedup vs baseline: 1.0007x; 1.0007x over previous
//
#include <hip/hip_runtime.h>

// VectorQuantizer: x (64,32,32,128) f32, embeddings (128,1024) f32.
// out = x + (q - x), q = e.T[argmin_k ||x_row - e_k||^2]
//
// Cascade (each stage only needs enough precision to RANK):
//   phase 1 (hi-bf16 MFMA, swapped operands A=codes/B=x-rows): per-row argmin
//     in-lane over packed keys (m = dot - nrm/2, 8-bit local code id in mantissa
//     LSBs); -nrm/2 folded in via 9th MFMA whose A-operand comes from REGISTERS
//     (hl[8] pre-loaded from global). Main t-loop is FULLY UNROLLED: r17 left it
//     rolled, so hl[t] was runtime-indexed -> private array demoted to scratch
//     (VGPR 128, 82 MB scratch WRITE, 73us). Static indexing keeps it in regs.
//     Grid = 256 rowgroups x 4 quarters (r15 geometry, best measured);
//     2 rowtiles/wave; top-2 via v_med3_f32; pb [q][row]; (256,2) no-spill cap.
//   k_finish (merge+gather fused): merge 4 quarters/row -> code; STE-gather;
//     gap < MARGIN1 -> worklist (provisional output, corrected by rescan).
//   k_rescan: EXACT f64 re-argmin of flagged rows (4 rows/block, r11-proven
//     register budget), writes corrected output rows directly.
// 4 dispatches (wlc cleared by prep).
// C/D layout col=lane&31, reg->(r&3)+8*(r>>2)+4*(lane>>5); k-bijection symmetry
// and the 9th-MFMA nrm trick verified end-to-end rounds 3-17 (absmax 0).

#define NROWS 65536
#define DDIM 128
#define KCODES 1024
#define MARGIN1 0.30f    // s-space; hi-bf16 sigma ~0.05, cid noise ~0.016

typedef __attribute__((ext_vector_type(8))) short short8;
typedef __attribute__((ext_vector_type(16))) float f32x16;

__device__ inline ushort f2bf(float f) {            // RNE f32 -> bf16 bits
    union { float f; unsigned u; } v; v.f = f;
    unsigned r = v.u + 0x7fffu + ((v.u >> 16) & 1u);
    return (ushort)(r >> 16);
}
__device__ inline float bf2f(ushort b) {
    union { unsigned u; float f; } v; v.u = ((unsigned)b) << 16;
    return v.f;
}

__device__ inline void gload_lds16(const uint4* g, uint4* lds) {
    __builtin_amdgcn_global_load_lds((const __attribute__((address_space(1))) void*)g,
                                     (__attribute__((address_space(3))) void*)lds,
                                     16, 0, 0);
}

// ---------- fused prep: transpose + norms + e-hi pack + nrm hi/lo + x-hi pack ----------
// grid 4096 x 256.
__global__ void k_prep(const float* __restrict__ x, const float* __restrict__ e,
                       float* __restrict__ et, double* __restrict__ nrm64,
                       uint4* __restrict__ epq, unsigned* __restrict__ nhl,
                       uint4* __restrict__ xp, int* __restrict__ wlc) {
    const int gid = blockIdx.x * blockDim.x + threadIdx.x;

    if (gid == 0) { wlc[0] = 0; wlc[1] = 0; }

    // x-hi fragment pack (all threads): xp[rt*512 + c*64 + lane]
    {
        int lane = gid & 63, c = (gid >> 6) & 7, rt = gid >> 9;     // rt 0..2047
        int row = rt * 32 + (lane & 31);
        int kbase = c * 16 + ((lane >> 5) << 3);
        const float4* xr4 = reinterpret_cast<const float4*>(x + (size_t)row * DDIM + kbase);
        float4 u = xr4[0], v = xr4[1];
        float fv[8] = {u.x, u.y, u.z, u.w, v.x, v.y, v.z, v.w};
        union { ushort s[8]; uint4 q; } pk;
        #pragma unroll
        for (int j = 0; j < 8; ++j) pk.s[j] = f2bf(fv[j]);
        xp[gid] = pk.q;
    }

    // transpose (first 131072): et[k][d] = e[d][k]
    if (gid < 131072) {
        int d = gid >> 10, k = gid & 1023;
        et[k * DDIM + d] = e[gid];
    }

    // e-hi fragment pack (first 16384): epq[nt*512 + c*64 + lane]
    if (gid < 16384) {
        int lane = gid & 63, c = (gid >> 6) & 7, nt = gid >> 9;
        int col = nt * 32 + (lane & 31);
        int kbase = c * 16 + ((lane >> 5) << 3);
        union { ushort s[8]; uint4 q; } pk;
        #pragma unroll
        for (int j = 0; j < 8; ++j)
            pk.s[j] = f2bf(e[(kbase + j) * KCODES + col]);
        epq[(size_t)nt * 512 + c * 64 + lane] = pk.q;
    }

    // norms (threads 32768..40959): 8 lanes per code, shfl reduce
    if (gid >= 32768 && gid < 32768 + 8192) {
        int t2 = gid - 32768;
        int k = t2 >> 3, part = t2 & 7;
        double s = 0.0;
        #pragma unroll
        for (int j = 0; j < 16; ++j) {
            double v = (double)e[(part * 16 + j) * KCODES + k];
            s = fma(v, v, s);
        }
        #pragma unroll
        for (int m = 1; m < 8; m <<= 1) s += __shfl_xor(s, m);
        if (part == 0) {
            nrm64[k] = s;
            float t0 = (float)(-0.5 * s);
            ushort hb = f2bf(t0);
            ushort lb = f2bf(t0 - bf2f(hb));
            nhl[k] = (unsigned)hb | ((unsigned)lb << 16);
        }
    }
}

// ---------- phase 1: swapped-operand hi-bf16 MFMA argmin, quarter-split ----------
// grid 1024 = 256 rowgroups x 4 quarters. Block = 4 waves; each wave owns TWO
// rowtiles (interleaved MFMA chains). 64 KB LDS stage-once; barrier-free,
// FULLY-UNROLLED main loop; nrm bias words in registers (static indexing).
__global__ __launch_bounds__(256, 2) void k_argmin32(const uint4* __restrict__ xp,
                                                     const uint4* __restrict__ epq,
                                                     const unsigned* __restrict__ nhl,
                                                     unsigned* __restrict__ pb1,
                                                     float* __restrict__ pb2) {
    __shared__ uint4 sbuf[4096];      // 64 KB: 8 e-hi tiles (256 codes)

    const int tid = threadIdx.x;
    const int lane = tid & 63;
    const int w = tid >> 6;
    const int kq = blockIdx.x & 3;                 // code quarter
    const int rg = blockIdx.x >> 2;                // rowgroup (256 rows)
    const int rtA = rg * 8 + w * 2;                // this wave's rowtiles
    const int rtB = rtA + 1;
    const int lrow = lane & 31;
    const int lgrp = lane >> 5;

    // stage quarter: 8 tiles (16 x 16B per thread)
    #pragma unroll
    for (int i = 0; i < 16; ++i)
        gload_lds16(epq + (size_t)kq * 4096 + i * 256 + tid,
                    &sbuf[i * 256 + (w << 6)]);

    // nrm bias words for this quarter's 8 tiles, straight to registers
    unsigned hl[8];
    #pragma unroll
    for (int t = 0; t < 8; ++t)
        hl[t] = nhl[kq * 256 + t * 32 + lrow];

    // x-hi fragments for both rowtiles (pre-packed, coalesced)
    short8 ahA[8], ahB[8];
    #pragma unroll
    for (int c = 0; c < 8; ++c) {
        union { uint4 q; short8 s; } ua, ub;
        ua.q = xp[(size_t)rtA * 512 + c * 64 + lane];
        ub.q = xp[(size_t)rtB * 512 + c * 64 + lane];
        ahA[c] = ua.s; ahB[c] = ub.s;
    }
    // 9th-MFMA B operand: ones at k=0,1
    short8 bx = {0, 0, 0, 0, 0, 0, 0, 0};
    if (lgrp == 0) { bx[0] = (short)0x3F80; bx[1] = (short)0x3F80; }
    const unsigned cid4 = (unsigned)(lgrp << 2);   // the only runtime cid bit

    asm volatile("s_waitcnt vmcnt(0)" ::: "memory");
    __syncthreads();                  // staged; barrier-free main loop

    float kA1 = -3.4e38f, kA2 = -3.4e38f;
    float kB1 = -3.4e38f, kB2 = -3.4e38f;

    #pragma unroll                    // REQUIRED: hl[t] must be static-indexed
    for (int t = 0; t < 8; ++t) {
        f32x16 aA, aB;
        #pragma unroll
        for (int r = 0; r < 16; ++r) { aA[r] = 0.f; aB[r] = 0.f; }

        #pragma unroll
        for (int c = 0; c < 8; ++c) {
            union { uint4 q; short8 s; } ef;
            ef.q = sbuf[t * 512 + c * 64 + lane];
            aA = __builtin_amdgcn_mfma_f32_32x32x16_bf16(ef.s, ahA[c], aA, 0, 0, 0);
            aB = __builtin_amdgcn_mfma_f32_32x32x16_bf16(ef.s, ahB[c], aB, 0, 0, 0);
        }
        short8 ax = {0, 0, 0, 0, 0, 0, 0, 0};
        if (lgrp == 0) {
            ax[0] = (short)(hl[t] & 0xFFFF);
            ax[1] = (short)(hl[t] >> 16);
        }
        aA = __builtin_amdgcn_mfma_f32_32x32x16_bf16(ax, bx, aA, 0, 0, 0);
        aB = __builtin_amdgcn_mfma_f32_32x32x16_bf16(ax, bx, aB, 0, 0, 0);

        // 3 VALU per key: v_and_or pack, v_med3 (new 2nd-best), v_max (new best)
        #pragma unroll
        for (int r = 0; r < 16; ++r) {
            unsigned cid = (unsigned)((t << 5) | ((r & 3) + ((r >> 2) << 3))) | cid4;
            float keyA = __uint_as_float((__float_as_uint(aA[r]) & 0xFFFFFF00u) | cid);
            float keyB = __uint_as_float((__float_as_uint(aB[r]) & 0xFFFFFF00u) | cid);
            kA2 = __builtin_amdgcn_fmed3f(kA1, kA2, keyA);
            kA1 = fmaxf(kA1, keyA);
            kB2 = __builtin_amdgcn_fmed3f(kB1, kB2, keyB);
            kB1 = fmaxf(kB1, keyB);
        }
    }

    // combine the two 32-lane halves (sorted-pair merge via med3)
    {
        float o1 = __shfl_xor(kA1, 32);
        float o2 = __shfl_xor(kA2, 32);
        float m2 = __builtin_amdgcn_fmed3f(kA1, o1, fmaxf(kA2, o2));
        float m1 = fmaxf(kA1, o1);
        if (lane < 32) {                           // coalesced 128B wave-half write
            size_t o = (size_t)kq * NROWS + rtA * 32 + lrow;
            pb1[o] = __float_as_uint(m1);
            pb2[o] = m2;
        }
    }
    {
        float o1 = __shfl_xor(kB1, 32);
        float o2 = __shfl_xor(kB2, 32);
        float m2 = __builtin_amdgcn_fmed3f(kB1, o1, fmaxf(kB2, o2));
        float m1 = fmaxf(kB1, o1);
        if (lane < 32) {
            size_t o = (size_t)kq * NROWS + rtB * 32 + lrow;
            pb1[o] = __float_as_uint(m1);
            pb2[o] = m2;
        }
    }
}

// ---------- k_finish: merge 4 quarters + STE-gather, fused ----------
// grid 256 x 256: block owns 256 rows. Phase A: per-thread merge -> code in LDS,
// flagged rows -> worklist. Phase B: block streams 256 rows x 32 float4 out.
__global__ __launch_bounds__(256) void k_finish(const float* __restrict__ x,
                                                const float* __restrict__ et,
                                                const unsigned* __restrict__ pb1,
                                                const float* __restrict__ pb2,
                                                int* __restrict__ wlc,
                                                int* __restrict__ wl,
                                                float* __restrict__ out) {
    __shared__ int scode[256];
    const int tid = threadIdx.x;
    const int base = blockIdx.x * 256;
    const int r = base + tid;

    // merge ([q][row] layout: coalesced per-q loads)
    float best = -3.4e38f, sec = -3.4e38f;
    unsigned ub = 0; int bq = 0;
    #pragma unroll
    for (int q = 0; q < 4; ++q) {
        unsigned k1 = pb1[(size_t)q * NROWS + r];
        float    s2 = __uint_as_float(__float_as_uint(pb2[(size_t)q * NROWS + r]) & 0xFFFFFF00u);
        float    m  = __uint_as_float(k1 & 0xFFFFFF00u);
        bool t = m > best;
        sec = fmaxf(sec, fmaxf(s2, t ? best : m));
        ub = t ? k1 : ub;
        bq = t ? q : bq;
        best = t ? m : best;
    }
    scode[tid] = bq * 256 + (int)(ub & 255u);
    if (2.f * (best - sec) < MARGIN1) {                // s-gap = 2*(m1-m2)
        int slot = atomicAdd(wlc, 1);
        wl[slot] = r;
    }
    __syncthreads();

    // STE-gather: 256 rows x 32 float4 = 8192 float4, 32 per thread
    const float4* x4  = reinterpret_cast<const float4*>(x);
    const float4* et4 = reinterpret_cast<const float4*>(et);
    float4* o4 = reinterpret_cast<float4*>(out);
    #pragma unroll
    for (int i = 0; i < 32; ++i) {
        int j = i * 256 + tid;                         // 0..8191
        int rl = j >> 5, d4 = j & 31;
        size_t g = (size_t)(base + rl) * 32 + d4;
        float4 q = et4[(size_t)scode[rl] * 32 + d4];
        float4 xv = x4[g];
        float4 o;
        o.x = xv.x + (q.x - xv.x);
        o.y = xv.y + (q.y - xv.y);
        o.z = xv.z + (q.z - xv.z);
        o.w = xv.w + (q.w - xv.w);
        o4[g] = o;
    }
}

// ---------- rescan: EXACT f64 re-argmin + direct output write ----------
// 4 rows/block (r11-proven register budget: acc[4][4] f64).
__global__ __launch_bounds__(256) void k_rescan(const float* __restrict__ x,
                                                const float* __restrict__ e,
                                                const float* __restrict__ et,
                                                const double* __restrict__ nrm64,
                                                const int* __restrict__ wlc,
                                                const int* __restrict__ wl,
                                                float* __restrict__ out) {
    __shared__ float  xs[4][DDIM];
    __shared__ double rb1[4][256];
    __shared__ int    ri[4][256];
    const int tid = threadIdx.x, lane = tid & 63, wv = tid >> 6;
    const int n = *wlc;

    for (int i0 = blockIdx.x * 4; i0 < n; i0 += gridDim.x * 4) {
        if (tid < 128) {                   // 4 rows x 32 float4
            int j = tid >> 5, d4 = tid & 31;
            int ii = i0 + j;
            int row = wl[ii < n ? ii : i0];
            *reinterpret_cast<float4*>(&xs[j][d4 * 4]) =
                *reinterpret_cast<const float4*>(&x[(size_t)row * DDIM + d4 * 4]);
        }
        __syncthreads();

        double acc[4][4];
        #pragma unroll
        for (int kk = 0; kk < 4; ++kk)
            #pragma unroll
            for (int j = 0; j < 4; ++j) acc[kk][j] = 0.0;

        for (int d = 0; d < DDIM; d += 2) {
            double xv0[4], xv1[4];
            #pragma unroll
            for (int j = 0; j < 4; ++j) {
                xv0[j] = (double)xs[j][d];
                xv1[j] = (double)xs[j][d + 1];
            }
            #pragma unroll
            for (int kk = 0; kk < 4; ++kk) {
                double ev0 = (double)e[d * KCODES + kk * 256 + tid];       // coalesced
                double ev1 = (double)e[(d + 1) * KCODES + kk * 256 + tid];
                #pragma unroll
                for (int j = 0; j < 4; ++j) {
                    acc[kk][j] = fma(ev0, xv0[j], acc[kk][j]);
                    acc[kk][j] = fma(ev1, xv1[j], acc[kk][j]);
                }
            }
        }

        #pragma unroll
        for (int j = 0; j < 4; ++j) {
            double b1 = 1e300; int bi = 0;
            #pragma unroll
            for (int kk = 0; kk < 4; ++kk) {
                int k = kk * 256 + tid;                 // ascending per thread
                double s = nrm64[k] - 2.0 * acc[kk][j];
                if (s < b1) { b1 = s; bi = k; }
            }
            rb1[j][tid] = b1; ri[j][tid] = bi;
        }
        __syncthreads();

        // wave wv reduces row wv (first-min tiebreak), then writes the output row
        {
            double b1 = 1e300; int bi = 0x7FFFFFFF;
            #pragma unroll
            for (int p = 0; p < 4; ++p) {
                int t2 = lane + p * 64;
                double o1 = rb1[wv][t2]; int oi = ri[wv][t2];
                bool take = (o1 < b1) || (o1 == b1 && oi < bi);
                b1 = take ? o1 : b1;
                bi = take ? oi : bi;
            }
            #pragma unroll
            for (int m = 1; m < 64; m <<= 1) {
                double o1 = __shfl_xor(b1, m);
                int    oi = __shfl_xor(bi, m);
                bool take = (o1 < b1) || (o1 == b1 && oi < bi);
                b1 = take ? o1 : b1;
                bi = take ? oi : bi;
            }
            if (i0 + wv < n && lane < 32) {            // all lanes hold bi now
                int row = wl[i0 + wv];
                float4 q = reinterpret_cast<const float4*>(et)[(size_t)bi * 32 + lane];
                float4 xv = *reinterpret_cast<const float4*>(&xs[wv][lane * 4]);
                float4 o;
                o.x = xv.x + (q.x - xv.x);
                o.y = xv.y + (q.y - xv.y);
                o.z = xv.z + (q.z - xv.z);
                o.w = xv.w + (q.w - xv.w);
                reinterpret_cast<float4*>(out)[(size_t)row * 32 + lane] = o;
            }
        }
        __syncthreads();
    }
}

extern "C" void kernel_launch(void* const* d_in, const int* in_sizes, int n_in,
                              void* d_out, int out_size, void* d_ws, size_t ws_size,
                              hipStream_t stream) {
    const float* x = (const float*)d_in[0];
    const float* e = (const float*)d_in[1];
    float* out = (float*)d_out;

    // ws layout (f32 slot units; all segments 16B-aligned). ~4.3 MB.
    double*   nrm64 = (double*)d_ws;                     // 2048 slots
    float*    et    = (float*)d_ws + 2048;               // 131072
    int*      wlc   = (int*)(et + 131072);               // 4
    int*      wl    = wlc + 4;                           // 65536
    uint4*    epq   = (uint4*)(wl + NROWS);              // 16384 uint4 (e hi)
    unsigned* nhl   = (unsigned*)(epq + 16384);          // 1024
    unsigned* pb1   = nhl + 1024;                        // 4*65536  [q][row]
    float*    pb2   = (float*)(pb1 + 4 * NROWS);         // 4*65536  [q][row]
    // x-hi fragment pack lives in d_out (16 MB < 32 MB); k_finish overwrites it.
    uint4*    xp    = (uint4*)d_out;

    k_prep<<<4096, 256, 0, stream>>>(x, e, et, nrm64, epq, nhl, xp, wlc);
    k_argmin32<<<1024, 256, 0, stream>>>(xp, epq, nhl, pb1, pb2);
    k_finish<<<NROWS / 256, 256, 0, stream>>>(x, et, pb1, pb2, wlc, wl, out);
    k_rescan<<<1024, 256, 0, stream>>>(x, e, et, nrm64, wlc, wl, out);
}

// Round 19
// 91.598 us; speedup vs baseline: 1.4992x; 1.4982x over previous
//
#include <hip/hip_runtime.h>

// VectorQuantizer: x (64,32,32,128) f32, embeddings (128,1024) f32.
// out = x + (q - x), q = e.T[argmin_k ||x_row - e_k||^2]
//
// ===== r15 configuration (measured best: 91.7 us) — REVERT, no new variables =====
// r17/r18 post-mortem: hoisting the per-tile nrm bias into registers (hl[8])
// spilled regardless of unrolling (identical counters both rounds: VGPR 128,
// 82 MB scratch WRITE). Full unroll extends multiple aA/aB accumulator live
// ranges; the r15 LDS-staged snhl keeps one pair live per t-iteration (VGPR 84).
// LDS-per-t read is the stable schedule. Register-promotion here is an anti-fix.
//
// Cascade (each stage only needs enough precision to RANK):
//   phase 1 (hi-bf16 MFMA, swapped operands A=codes/B=x-rows): per-row argmin
//     in-lane over packed keys (m = dot - nrm/2, 8-bit local code id in mantissa
//     LSBs); -nrm/2 folded in via 9th MFMA (A-operand from snhl LDS).
//     Grid = 256 rowgroups x 4 quarters; 2 rowtiles/wave (interleaved chains);
//     top-2 via v_med3_f32; pb [q][row] (coalesced 128B wave-half writes).
//     (256,2): proven no-spill cap (r13: (256,3) -> 84 arch VGPRs -> spill).
//   k_finish (merge+gather fused): merge 4 quarters/row -> code; STE-gather;
//     gap < MARGIN1 -> worklist (provisional output, corrected by rescan).
//   k_rescan: EXACT f64 re-argmin of flagged rows (4 rows/block, r11-proven
//     register budget -- 8-row acc[4][8] spilled in r12), writes out directly.
// 4 dispatches (wlc cleared by prep).
// C/D layout col=lane&31, reg->(r&3)+8*(r>>2)+4*(lane>>5); k-bijection symmetry
// and the 9th-MFMA nrm trick verified end-to-end rounds 3-18 (absmax 0).

#define NROWS 65536
#define DDIM 128
#define KCODES 1024
#define MARGIN1 0.30f    // s-space; hi-bf16 sigma ~0.05, cid noise ~0.016

typedef __attribute__((ext_vector_type(8))) short short8;
typedef __attribute__((ext_vector_type(16))) float f32x16;

__device__ inline ushort f2bf(float f) {            // RNE f32 -> bf16 bits
    union { float f; unsigned u; } v; v.f = f;
    unsigned r = v.u + 0x7fffu + ((v.u >> 16) & 1u);
    return (ushort)(r >> 16);
}
__device__ inline float bf2f(ushort b) {
    union { unsigned u; float f; } v; v.u = ((unsigned)b) << 16;
    return v.f;
}

__device__ inline void gload_lds16(const uint4* g, uint4* lds) {
    __builtin_amdgcn_global_load_lds((const __attribute__((address_space(1))) void*)g,
                                     (__attribute__((address_space(3))) void*)lds,
                                     16, 0, 0);
}

// ---------- fused prep: transpose + norms + e-hi pack + nrm hi/lo + x-hi pack ----------
// grid 4096 x 256.
__global__ void k_prep(const float* __restrict__ x, const float* __restrict__ e,
                       float* __restrict__ et, float* __restrict__ nrm,
                       double* __restrict__ nrm64, uint4* __restrict__ epq,
                       unsigned* __restrict__ nhl, uint4* __restrict__ xp,
                       int* __restrict__ wlc) {
    const int gid = blockIdx.x * blockDim.x + threadIdx.x;

    if (gid == 0) { wlc[0] = 0; wlc[1] = 0; }

    // x-hi fragment pack (all threads): xp[rt*512 + c*64 + lane]
    {
        int lane = gid & 63, c = (gid >> 6) & 7, rt = gid >> 9;     // rt 0..2047
        int row = rt * 32 + (lane & 31);
        int kbase = c * 16 + ((lane >> 5) << 3);
        const float4* xr4 = reinterpret_cast<const float4*>(x + (size_t)row * DDIM + kbase);
        float4 u = xr4[0], v = xr4[1];
        float fv[8] = {u.x, u.y, u.z, u.w, v.x, v.y, v.z, v.w};
        union { ushort s[8]; uint4 q; } pk;
        #pragma unroll
        for (int j = 0; j < 8; ++j) pk.s[j] = f2bf(fv[j]);
        xp[gid] = pk.q;
    }

    // transpose (first 131072): et[k][d] = e[d][k]
    if (gid < 131072) {
        int d = gid >> 10, k = gid & 1023;
        et[k * DDIM + d] = e[gid];
    }

    // e-hi fragment pack (first 16384): epq[nt*512 + c*64 + lane]
    if (gid < 16384) {
        int lane = gid & 63, c = (gid >> 6) & 7, nt = gid >> 9;
        int col = nt * 32 + (lane & 31);
        int kbase = c * 16 + ((lane >> 5) << 3);
        union { ushort s[8]; uint4 q; } pk;
        #pragma unroll
        for (int j = 0; j < 8; ++j)
            pk.s[j] = f2bf(e[(kbase + j) * KCODES + col]);
        epq[(size_t)nt * 512 + c * 64 + lane] = pk.q;
    }

    // norms (threads 32768..40959): 8 lanes per code, shfl reduce
    if (gid >= 32768 && gid < 32768 + 8192) {
        int t2 = gid - 32768;
        int k = t2 >> 3, part = t2 & 7;
        double s = 0.0;
        #pragma unroll
        for (int j = 0; j < 16; ++j) {
            double v = (double)e[(part * 16 + j) * KCODES + k];
            s = fma(v, v, s);
        }
        #pragma unroll
        for (int m = 1; m < 8; m <<= 1) s += __shfl_xor(s, m);
        if (part == 0) {
            nrm64[k] = s; nrm[k] = (float)s;
            float t0 = (float)(-0.5 * s);
            ushort hb = f2bf(t0);
            ushort lb = f2bf(t0 - bf2f(hb));
            nhl[k] = (unsigned)hb | ((unsigned)lb << 16);
        }
    }
}

// ---------- phase 1: swapped-operand hi-bf16 MFMA argmin, quarter-split ----------
// grid 1024 = 256 rowgroups x 4 quarters. Block = 4 waves; each wave owns TWO
// rowtiles (interleaved MFMA chains). 65.5 KB LDS stage-once; barrier-free loop.
__global__ __launch_bounds__(256, 2) void k_argmin32(const uint4* __restrict__ xp,
                                                     const uint4* __restrict__ epq,
                                                     const unsigned* __restrict__ nhl,
                                                     unsigned* __restrict__ pb1,
                                                     float* __restrict__ pb2) {
    __shared__ uint4 sbuf[4096];      // 64 KB: 8 e-hi tiles (256 codes)
    __shared__ unsigned snhl[256];    // 1 KB: this quarter's -nrm/2 hi/lo

    const int tid = threadIdx.x;
    const int lane = tid & 63;
    const int w = tid >> 6;
    const int kq = blockIdx.x & 3;                 // code quarter
    const int rg = blockIdx.x >> 2;                // rowgroup (256 rows)
    const int rtA = rg * 8 + w * 2;                // this wave's rowtiles
    const int rtB = rtA + 1;
    const int lrow = lane & 31;
    const int lgrp = lane >> 5;

    // stage quarter: 8 tiles (16 x 16B per thread) + nhl slice (wave 0)
    #pragma unroll
    for (int i = 0; i < 16; ++i)
        gload_lds16(epq + (size_t)kq * 4096 + i * 256 + tid,
                    &sbuf[i * 256 + (w << 6)]);
    if (tid < 64)
        gload_lds16(reinterpret_cast<const uint4*>(nhl) + kq * 64 + tid,
                    reinterpret_cast<uint4*>(snhl));

    // x-hi fragments for both rowtiles (pre-packed, coalesced)
    short8 ahA[8], ahB[8];
    #pragma unroll
    for (int c = 0; c < 8; ++c) {
        union { uint4 q; short8 s; } ua, ub;
        ua.q = xp[(size_t)rtA * 512 + c * 64 + lane];
        ub.q = xp[(size_t)rtB * 512 + c * 64 + lane];
        ahA[c] = ua.s; ahB[c] = ub.s;
    }
    // 9th-MFMA B operand: ones at k=0,1
    short8 bx = {0, 0, 0, 0, 0, 0, 0, 0};
    if (lgrp == 0) { bx[0] = (short)0x3F80; bx[1] = (short)0x3F80; }
    const unsigned cid4 = (unsigned)(lgrp << 2);   // the only runtime cid bit

    asm volatile("s_waitcnt vmcnt(0)" ::: "memory");
    __syncthreads();                  // staged; barrier-free main loop

    float kA1 = -3.4e38f, kA2 = -3.4e38f;
    float kB1 = -3.4e38f, kB2 = -3.4e38f;

    for (int t = 0; t < 8; ++t) {
        f32x16 aA, aB;
        #pragma unroll
        for (int r = 0; r < 16; ++r) { aA[r] = 0.f; aB[r] = 0.f; }

        #pragma unroll
        for (int c = 0; c < 8; ++c) {
            union { uint4 q; short8 s; } ef;
            ef.q = sbuf[t * 512 + c * 64 + lane];
            aA = __builtin_amdgcn_mfma_f32_32x32x16_bf16(ef.s, ahA[c], aA, 0, 0, 0);
            aB = __builtin_amdgcn_mfma_f32_32x32x16_bf16(ef.s, ahB[c], aB, 0, 0, 0);
        }
        unsigned hl = snhl[t * 32 + lrow];
        short8 ax = {0, 0, 0, 0, 0, 0, 0, 0};
        if (lgrp == 0) { ax[0] = (short)(hl & 0xFFFF); ax[1] = (short)(hl >> 16); }
        aA = __builtin_amdgcn_mfma_f32_32x32x16_bf16(ax, bx, aA, 0, 0, 0);
        aB = __builtin_amdgcn_mfma_f32_32x32x16_bf16(ax, bx, aB, 0, 0, 0);

        // 3 VALU per key: v_and_or pack, v_med3 (new 2nd-best), v_max (new best)
        #pragma unroll
        for (int r = 0; r < 16; ++r) {
            unsigned cid = (unsigned)((t << 5) | ((r & 3) + ((r >> 2) << 3))) | cid4;
            float keyA = __uint_as_float((__float_as_uint(aA[r]) & 0xFFFFFF00u) | cid);
            float keyB = __uint_as_float((__float_as_uint(aB[r]) & 0xFFFFFF00u) | cid);
            kA2 = __builtin_amdgcn_fmed3f(kA1, kA2, keyA);
            kA1 = fmaxf(kA1, keyA);
            kB2 = __builtin_amdgcn_fmed3f(kB1, kB2, keyB);
            kB1 = fmaxf(kB1, keyB);
        }
    }

    // combine the two 32-lane halves (sorted-pair merge via med3)
    {
        float o1 = __shfl_xor(kA1, 32);
        float o2 = __shfl_xor(kA2, 32);
        float m2 = __builtin_amdgcn_fmed3f(kA1, o1, fmaxf(kA2, o2));
        float m1 = fmaxf(kA1, o1);
        if (lane < 32) {                           // coalesced 128B wave-half write
            size_t o = (size_t)kq * NROWS + rtA * 32 + lrow;
            pb1[o] = __float_as_uint(m1);
            pb2[o] = m2;
        }
    }
    {
        float o1 = __shfl_xor(kB1, 32);
        float o2 = __shfl_xor(kB2, 32);
        float m2 = __builtin_amdgcn_fmed3f(kB1, o1, fmaxf(kB2, o2));
        float m1 = fmaxf(kB1, o1);
        if (lane < 32) {
            size_t o = (size_t)kq * NROWS + rtB * 32 + lrow;
            pb1[o] = __float_as_uint(m1);
            pb2[o] = m2;
        }
    }
}

// ---------- k_finish: merge 4 quarters + STE-gather, fused ----------
// grid 256 x 256: block owns 256 rows. Phase A: per-thread merge -> code in LDS,
// flagged rows -> worklist. Phase B: block streams 256 rows x 32 float4 out.
__global__ __launch_bounds__(256) void k_finish(const float* __restrict__ x,
                                                const float* __restrict__ et,
                                                const unsigned* __restrict__ pb1,
                                                const float* __restrict__ pb2,
                                                int* __restrict__ wlc,
                                                int* __restrict__ wl,
                                                float* __restrict__ out) {
    __shared__ int scode[256];
    const int tid = threadIdx.x;
    const int base = blockIdx.x * 256;
    const int r = base + tid;

    // merge ([q][row] layout: coalesced per-q loads)
    float best = -3.4e38f, sec = -3.4e38f;
    unsigned ub = 0; int bq = 0;
    #pragma unroll
    for (int q = 0; q < 4; ++q) {
        unsigned k1 = pb1[(size_t)q * NROWS + r];
        float    s2 = __uint_as_float(__float_as_uint(pb2[(size_t)q * NROWS + r]) & 0xFFFFFF00u);
        float    m  = __uint_as_float(k1 & 0xFFFFFF00u);
        bool t = m > best;
        sec = fmaxf(sec, fmaxf(s2, t ? best : m));
        ub = t ? k1 : ub;
        bq = t ? q : bq;
        best = t ? m : best;
    }
    scode[tid] = bq * 256 + (int)(ub & 255u);
    if (2.f * (best - sec) < MARGIN1) {                // s-gap = 2*(m1-m2)
        int slot = atomicAdd(wlc, 1);
        wl[slot] = r;
    }
    __syncthreads();

    // STE-gather: 256 rows x 32 float4 = 8192 float4, 32 per thread
    const float4* x4  = reinterpret_cast<const float4*>(x);
    const float4* et4 = reinterpret_cast<const float4*>(et);
    float4* o4 = reinterpret_cast<float4*>(out);
    #pragma unroll
    for (int i = 0; i < 32; ++i) {
        int j = i * 256 + tid;                         // 0..8191
        int rl = j >> 5, d4 = j & 31;
        size_t g = (size_t)(base + rl) * 32 + d4;
        float4 q = et4[(size_t)scode[rl] * 32 + d4];
        float4 xv = x4[g];
        float4 o;
        o.x = xv.x + (q.x - xv.x);
        o.y = xv.y + (q.y - xv.y);
        o.z = xv.z + (q.z - xv.z);
        o.w = xv.w + (q.w - xv.w);
        o4[g] = o;
    }
}

// ---------- rescan: EXACT f64 re-argmin + direct output write ----------
// 4 rows/block (r11-proven register budget: acc[4][4] f64).
__global__ __launch_bounds__(256) void k_rescan(const float* __restrict__ x,
                                                const float* __restrict__ e,
                                                const float* __restrict__ et,
                                                const double* __restrict__ nrm64,
                                                const int* __restrict__ wlc,
                                                const int* __restrict__ wl,
                                                float* __restrict__ out) {
    __shared__ float  xs[4][DDIM];
    __shared__ double rb1[4][256];
    __shared__ int    ri[4][256];
    const int tid = threadIdx.x, lane = tid & 63, wv = tid >> 6;
    const int n = *wlc;

    for (int i0 = blockIdx.x * 4; i0 < n; i0 += gridDim.x * 4) {
        if (tid < 128) {                   // 4 rows x 32 float4
            int j = tid >> 5, d4 = tid & 31;
            int ii = i0 + j;
            int row = wl[ii < n ? ii : i0];
            *reinterpret_cast<float4*>(&xs[j][d4 * 4]) =
                *reinterpret_cast<const float4*>(&x[(size_t)row * DDIM + d4 * 4]);
        }
        __syncthreads();

        double acc[4][4];
        #pragma unroll
        for (int kk = 0; kk < 4; ++kk)
            #pragma unroll
            for (int j = 0; j < 4; ++j) acc[kk][j] = 0.0;

        for (int d = 0; d < DDIM; d += 2) {
            double xv0[4], xv1[4];
            #pragma unroll
            for (int j = 0; j < 4; ++j) {
                xv0[j] = (double)xs[j][d];
                xv1[j] = (double)xs[j][d + 1];
            }
            #pragma unroll
            for (int kk = 0; kk < 4; ++kk) {
                double ev0 = (double)e[d * KCODES + kk * 256 + tid];       // coalesced
                double ev1 = (double)e[(d + 1) * KCODES + kk * 256 + tid];
                #pragma unroll
                for (int j = 0; j < 4; ++j) {
                    acc[kk][j] = fma(ev0, xv0[j], acc[kk][j]);
                    acc[kk][j] = fma(ev1, xv1[j], acc[kk][j]);
                }
            }
        }

        #pragma unroll
        for (int j = 0; j < 4; ++j) {
            double b1 = 1e300; int bi = 0;
            #pragma unroll
            for (int kk = 0; kk < 4; ++kk) {
                int k = kk * 256 + tid;                 // ascending per thread
                double s = nrm64[k] - 2.0 * acc[kk][j];
                if (s < b1) { b1 = s; bi = k; }
            }
            rb1[j][tid] = b1; ri[j][tid] = bi;
        }
        __syncthreads();

        // wave wv reduces row wv (first-min tiebreak), then writes the output row
        {
            double b1 = 1e300; int bi = 0x7FFFFFFF;
            #pragma unroll
            for (int p = 0; p < 4; ++p) {
                int t2 = lane + p * 64;
                double o1 = rb1[wv][t2]; int oi = ri[wv][t2];
                bool take = (o1 < b1) || (o1 == b1 && oi < bi);
                b1 = take ? o1 : b1;
                bi = take ? oi : bi;
            }
            #pragma unroll
            for (int m = 1; m < 64; m <<= 1) {
                double o1 = __shfl_xor(b1, m);
                int    oi = __shfl_xor(bi, m);
                bool take = (o1 < b1) || (o1 == b1 && oi < bi);
                b1 = take ? o1 : b1;
                bi = take ? oi : bi;
            }
            if (i0 + wv < n && lane < 32) {            // all lanes hold bi now
                int row = wl[i0 + wv];
                float4 q = reinterpret_cast<const float4*>(et)[(size_t)bi * 32 + lane];
                float4 xv = *reinterpret_cast<const float4*>(&xs[wv][lane * 4]);
                float4 o;
                o.x = xv.x + (q.x - xv.x);
                o.y = xv.y + (q.y - xv.y);
                o.z = xv.z + (q.z - xv.z);
                o.w = xv.w + (q.w - xv.w);
                reinterpret_cast<float4*>(out)[(size_t)row * 32 + lane] = o;
            }
        }
        __syncthreads();
    }
}

extern "C" void kernel_launch(void* const* d_in, const int* in_sizes, int n_in,
                              void* d_out, int out_size, void* d_ws, size_t ws_size,
                              hipStream_t stream) {
    const float* x = (const float*)d_in[0];
    const float* e = (const float*)d_in[1];
    float* out = (float*)d_out;

    // ws layout (f32 slot units; all segments 16B-aligned). ~4.3 MB.
    double*   nrm64 = (double*)d_ws;                     // 2048 slots
    float*    et    = (float*)d_ws + 2048;               // 131072
    float*    nrm   = et + 131072;                       // 1024
    int*      wlc   = (int*)(nrm + 1024);                // 4
    int*      wl    = wlc + 4;                           // 65536
    uint4*    epq   = (uint4*)(wl + NROWS);              // 16384 uint4 (e hi)
    unsigned* nhl   = (unsigned*)(epq + 16384);          // 1024
    unsigned* pb1   = nhl + 1024;                        // 4*65536  [q][row]
    float*    pb2   = (float*)(pb1 + 4 * NROWS);         // 4*65536  [q][row]
    // x-hi fragment pack lives in d_out (16 MB < 32 MB); k_finish overwrites it.
    uint4*    xp    = (uint4*)d_out;

    k_prep<<<4096, 256, 0, stream>>>(x, e, et, nrm, nrm64, epq, nhl, xp, wlc);
    k_argmin32<<<1024, 256, 0, stream>>>(xp, epq, nhl, pb1, pb2);
    k_finish<<<NROWS / 256, 256, 0, stream>>>(x, et, pb1, pb2, wlc, wl, out);
    k_rescan<<<1024, 256, 0, stream>>>(x, e, et, nrm64, wlc, wl, out);
}